// Round 23
// baseline (134.050 us; speedup 1.0000x reference)
//
#include <hip/hip_runtime.h>
#include <stdint.h>

typedef int i32x4  __attribute__((ext_vector_type(4)));
typedef int i32x16 __attribute__((ext_vector_type(16)));

static constexpr int Mdim   = 16384;     // B*S = 8*2048
static constexpr int Kdim   = 2048;      // D_IN
static constexpr int Ndim   = 2048;      // D_OUT
static constexpr int WELEMS = Ndim * Kdim;   // 4194304

// Fragment-major pack layout (shared by packers and GEMM):
//   chunk(R, c) = 1024 B at base + (R*64 + c)*1024
//   byte l*16 + b of a chunk holds row R*32 + (l&31), k = c*32 + (l>>5)*16 + b

// ---------------- async global->LDS (16B per lane, lane-ordered dest) -------
__device__ __forceinline__ void gload_lds16(const void* g, void* l) {
  __builtin_amdgcn_global_load_lds(
      (const __attribute__((address_space(1))) void*)g,
      (__attribute__((address_space(3))) void*)l,
      16, 0, 0);
}

// ---------------- K1: partial sums of |w| -----------------------------------
__global__ void k_abs_part(const float* __restrict__ w, float* __restrict__ part) {
  const float4* w4 = (const float4*)w;
  float s = 0.f;
  int idx = blockIdx.x * 256 + threadIdx.x;
  #pragma unroll 4
  for (int i = idx; i < WELEMS / 4; i += 256 * 256) {
    float4 v = w4[i];
    s += fabsf(v.x) + fabsf(v.y) + fabsf(v.z) + fabsf(v.w);
  }
  #pragma unroll
  for (int off = 32; off > 0; off >>= 1) s += __shfl_down(s, off);
  __shared__ float sm[4];
  if ((threadIdx.x & 63) == 0) sm[threadIdx.x >> 6] = s;
  __syncthreads();
  if (threadIdx.x == 0) part[blockIdx.x] = sm[0] + sm[1] + sm[2] + sm[3];
}

__device__ __forceinline__ int quant4(float4 v, float sc) {
  int a = (int)rintf(v.x / sc); a = a < -128 ? -128 : (a > 127 ? 127 : a);
  int b = (int)rintf(v.y / sc); b = b < -128 ? -128 : (b > 127 ? 127 : b);
  int c = (int)rintf(v.z / sc); c = c < -128 ? -128 : (c > 127 ? 127 : c);
  int d = (int)rintf(v.w / sc); d = d < -128 ? -128 : (d > 127 ? 127 : d);
  return (a & 255) | ((b & 255) << 8) | ((c & 255) << 16) | ((d & 255) << 24);
}

__device__ __forceinline__ int tern4(float4 v, float s) {
  int a = (int)rintf(v.x / s); a = a < -1 ? -1 : (a > 1 ? 1 : a);
  int b = (int)rintf(v.y / s); b = b < -1 ? -1 : (b > 1 ? 1 : b);
  int c = (int)rintf(v.z / s); c = c < -1 ? -1 : (c > 1 ? 1 : c);
  int d = (int)rintf(v.w / s); d = d < -1 ? -1 : (d > 1 ? 1 : d);
  return (a & 255) | ((b & 255) << 8) | ((c & 255) << 16) | ((d & 255) << 24);
}

// LDS row stride for the transpose buffers: 2052 B (513 dwords, odd ->
// bank = (l*513 + k)%32 spreads 32 rows over all 32 banks; <=2-way = free).
static constexpr int LSTR = 2052;

// ---------------- K3: ternary weight quantize + pack (inlines the scale) ----
__global__ __launch_bounds__(512) void k_wquant(const float* __restrict__ w,
                                                char* __restrict__ wq,
                                                const float* __restrict__ part) {
  __shared__ char sq[32 * LSTR];
  __shared__ float smr[8];
  const int wv = threadIdx.x >> 6;       // 0..7
  const int l  = threadIdx.x & 63;

  // ---- inline scale = mean(|w|): reduce part[0..255] ----
  float ps = (threadIdx.x < 256) ? part[threadIdx.x] : 0.f;
  #pragma unroll
  for (int off = 32; off > 0; off >>= 1) ps += __shfl_down(ps, off);
  if (l == 0) smr[wv] = ps;
  __syncthreads();
  const float s = (smr[0] + smr[1] + smr[2] + smr[3] +
                   smr[4] + smr[5] + smr[6] + smr[7]) / (float)WELEMS + 1e-8f;

  const int Rg = blockIdx.x;
  #pragma unroll
  for (int it = 0; it < 4; ++it) {
    const int rs = it * 8 + wv;          // row slot 0..31
    const float4* wr = (const float4*)(w + (size_t)(Rg * 32 + rs) * Kdim);
    #pragma unroll
    for (int c = 0; c < 8; ++c)
      *(int*)(&sq[rs * LSTR + (c * 64 + l) * 4]) = tern4(wr[c * 64 + l], s);
  }
  __syncthreads();
  char* dst = wq + (size_t)Rg * 65536;
  #pragma unroll
  for (int i = 0; i < 8; ++i) {
    const int c = i * 8 + wv;            // chunk 0..63
    int p[4];
    #pragma unroll
    for (int j = 0; j < 4; ++j)
      p[j] = *(const int*)(&sq[(l & 31) * LSTR + c * 32 + (l >> 5) * 16 + j * 4]);
    *(int4*)(dst + c * 1024 + l * 16) = make_int4(p[0], p[1], p[2], p[3]);
  }
}

// ---------------- K4: per-row absmax + int8 quantize + pack -----------------
__global__ __launch_bounds__(512) void k_xquant(const float* __restrict__ x,
                                                char* __restrict__ xq,
                                                float* __restrict__ xs) {
  __shared__ char sq[32 * LSTR];
  const int Rg = blockIdx.x;
  const int wv = threadIdx.x >> 6;       // 0..7
  const int l  = threadIdx.x & 63;

  #pragma unroll
  for (int it = 0; it < 4; ++it) {
    const int rs  = it * 8 + wv;
    const int row = Rg * 32 + rs;
    const float4* xr = (const float4*)(x + (size_t)row * Kdim);
    float4 v[8];
    float  m = 0.f;
    #pragma unroll
    for (int c = 0; c < 8; ++c) {
      v[c] = xr[c * 64 + l];
      m = fmaxf(m, fmaxf(fmaxf(fabsf(v[c].x), fabsf(v[c].y)),
                         fmaxf(fabsf(v[c].z), fabsf(v[c].w))));
    }
    #pragma unroll
    for (int off = 1; off < 64; off <<= 1) m = fmaxf(m, __shfl_xor(m, off));
    m = fmaxf(m, 1e-8f);
    const float sc = m / 127.0f;
    if (l == 0) xs[row] = sc;
    #pragma unroll
    for (int c = 0; c < 8; ++c)
      *(int*)(&sq[rs * LSTR + (c * 64 + l) * 4]) = quant4(v[c], sc);
  }
  __syncthreads();
  char* dst = xq + (size_t)Rg * 65536;
  #pragma unroll
  for (int i = 0; i < 8; ++i) {
    const int c = i * 8 + wv;
    int p[4];
    #pragma unroll
    for (int j = 0; j < 4; ++j)
      p[j] = *(const int*)(&sq[(l & 31) * LSTR + c * 32 + (l >> 5) * 16 + j * 4]);
    *(int4*)(dst + c * 1024 + l * 16) = make_int4(p[0], p[1], p[2], p[3]);
  }
}

// ---------------- K5: int8 MFMA GEMM, 256x128, RING-3, 1 barrier, reads-first
// out = (scale*xs[m]) * (xq . wq^T) + bias
// R22 minus barrier #2 (isolates: reads-first ordering vs convergence drain).
// 512 thr = 8 waves (4M x 2N), wave tile 64x64 = acc[2][2] (64 AGPR, total
// regs <= 128 -> 4 waves/SIMD; 2 blocks/CU = 16 waves).  Ring-3 x 24 KiB.
// Per tile: {vmcnt(3); s_barrier; ds_reads(t); STAGE(t+2); setprio MFMA}.
// Safety (R21-proven): reads(t) follow a barrier preceded by EVERY wave's
// vmcnt(3) (tile-t DMA globally confirmed); STAGE(t+2) targets buf[(t-1)%3]
// whose reads were consumed by MFMA(t-1) lgkm waits before any wave reached
// barrier t; its DMA lands >=200cy after issue, long after other waves'
// pre-barrier ds_reads completed.  vmcnt never 0 until the peeled last tile.
__global__ __launch_bounds__(512, 4) void k_gemm(
    const char* __restrict__ xq, const char* __restrict__ wq,
    const float* __restrict__ xs, const float* __restrict__ scal_part,
    const float* __restrict__ bias, float* __restrict__ out) {
  __shared__ __attribute__((aligned(128))) char lds[3][24576];

  // XCD-aware bijective swizzle: 1024 blocks, 1024 % 8 == 0.
  const int hw  = blockIdx.x;
  const int lin = (hw & 7) * 128 + (hw >> 3);
  const int bm  = lin >> 4;               // 64 M-tiles (256 rows)
  const int bn  = lin & 15;               // 16 N-tiles (128 cols)

  const int tid = threadIdx.x;
  const int w   = tid >> 6;               // wave 0..7
  const int l   = tid & 63;
  const int wr  = w >> 1, wc = w & 1;     // 4 x 2 wave grid
  const int l16 = l * 16;

  // scale = mean(|w|): in-wave reduce of part[256] (4 vals/lane)
  float ps = scal_part[l] + scal_part[l + 64] + scal_part[l + 128] + scal_part[l + 192];
  #pragma unroll
  for (int off = 32; off > 0; off >>= 1) ps += __shfl_down(ps, off);
  const float wsc = __shfl(ps, 0) / (float)WELEMS;

  // staging map: q = w*3+j over 24 chunks = [A: rg 0..7 x ks 0,1][B: rg 0..3 x ks 0,1]
  const char* gsrc[3];
  int         loff[3];
  #pragma unroll
  for (int j = 0; j < 3; ++j) {
    const int q = w * 3 + j;             // wave-uniform
    if (q < 16) {
      const int rg = q >> 1, ks = q & 1;
      gsrc[j] = xq + (size_t)(bm * 8 + rg) * 65536 + ks * 1024 + l16;
      loff[j] = rg * 2048 + ks * 1024;
    } else {
      const int p = q - 16, rg = p >> 1, ks = p & 1;
      gsrc[j] = wq + (size_t)(bn * 4 + rg) * 65536 + ks * 1024 + l16;
      loff[j] = 16384 + rg * 2048 + ks * 1024;
    }
  }

#define STAGE(t_, buf_)                                                   \
  { const size_t kb_ = (size_t)(t_) * 2048;                               \
    gload_lds16(gsrc[0] + kb_, &lds[buf_][loff[0]]);                      \
    gload_lds16(gsrc[1] + kb_, &lds[buf_][loff[1]]);                      \
    gload_lds16(gsrc[2] + kb_, &lds[buf_][loff[2]]); }

  i32x16 acc[2][2] = {};

  STAGE(0, 0); STAGE(1, 1);               // 6 per-wave loads in flight

#define TILE(T_, RB_, SB_, VMTOK, DOSTG)                                    \
  {                                                                         \
    VMTOK                                                                   \
    __builtin_amdgcn_s_barrier();                                           \
    asm volatile("" ::: "memory");                                          \
    const char* base_ = &lds[RB_][0];                                       \
    i32x4 aF[2][2], bF[2][2];                                               \
    _Pragma("unroll") for (int mi = 0; mi < 2; ++mi)                        \
      _Pragma("unroll") for (int ks = 0; ks < 2; ++ks)                      \
        aF[mi][ks] = *(const i32x4*)(base_ + ((wr*2+mi)*2+ks)*1024 + l16);  \
    _Pragma("unroll") for (int ni = 0; ni < 2; ++ni)                        \
      _Pragma("unroll") for (int ks = 0; ks < 2; ++ks)                      \
        bF[ni][ks] = *(const i32x4*)(base_ + 16384 + ((wc*2+ni)*2+ks)*1024 + l16); \
    if (DOSTG) STAGE((T_) + 2, SB_)                                         \
    __builtin_amdgcn_s_setprio(1);                                          \
    _Pragma("unroll") for (int ks = 0; ks < 2; ++ks)                        \
      _Pragma("unroll") for (int mi = 0; mi < 2; ++mi)                      \
        _Pragma("unroll") for (int ni = 0; ni < 2; ++ni)                    \
          acc[mi][ni] = __builtin_amdgcn_mfma_i32_32x32x32_i8(              \
              aF[mi][ks], bF[ni][ks], acc[mi][ni], 0, 0, 0);                \
    __builtin_amdgcn_s_setprio(0);                                          \
  }

#define VM3  asm volatile("s_waitcnt vmcnt(3)" ::: "memory");
#define VM0  asm volatile("s_waitcnt vmcnt(0)" ::: "memory");

  for (int t = 0; t < 30; t += 3) {       // tiles 0..29, static ring-3 idx
    TILE(t,     0, 2, VM3, 1);            // read buf0, stage t+2 -> buf2
    TILE(t + 1, 1, 0, VM3, 1);            // read buf1, stage t+3 -> buf0
    TILE(t + 2, 2, 1, VM3, 1);            // read buf2, stage t+4 -> buf1
  }
  TILE(30, 0, 0, VM3, 0);                 // tile 31's 3 loads stay in flight
  TILE(31, 1, 0, VM0, 0);                 // queue empties (last tile only)
#undef TILE
#undef STAGE
#undef VM3
#undef VM0

  // epilogue: C/D mapping col = lane&31, row = (r&3) + 8*(r>>2) + 4*(lane>>5)
  const int lhi = (l >> 5) * 4, lcol = l & 31;
  float bc[2];
  #pragma unroll
  for (int ni = 0; ni < 2; ++ni)
    bc[ni] = bias[bn * 128 + wc * 64 + ni * 32 + lcol];

  #pragma unroll
  for (int mi = 0; mi < 2; ++mi) {
    const int rb = bm * 256 + wr * 64 + mi * 32 + lhi;
    #pragma unroll
    for (int r = 0; r < 16; ++r) {
      const int   row = rb + (r & 3) + 8 * (r >> 2);
      const float sv  = wsc * xs[row];
      #pragma unroll
      for (int ni = 0; ni < 2; ++ni) {
        const int col = bn * 128 + wc * 64 + ni * 32 + lcol;
        out[(size_t)row * Ndim + col] = (float)acc[mi][ni][r] * sv + bc[ni];
      }
    }
  }
}

// ---------------- launch -----------------------------------------------------
extern "C" void kernel_launch(void* const* d_in, const int* in_sizes, int n_in,
                              void* d_out, int out_size, void* d_ws, size_t ws_size,
                              hipStream_t stream) {
  const float* x    = (const float*)d_in[0];
  const float* wgt  = (const float*)d_in[1];
  const float* bias = (const float*)d_in[2];
  float* out = (float*)d_out;

  float* ws_f = (float*)d_ws;
  float* part = ws_f + 64;          // 256 floats
  float* xs   = ws_f + 1024;        // 16384 floats
  char*  wq   = (char*)(ws_f + 20480);          // 4 MiB packed, 16B-aligned
  char*  xq   = wq + (size_t)WELEMS;            // 32 MiB packed, 16B-aligned

  hipLaunchKernelGGL(k_abs_part,  dim3(256),      dim3(256), 0, stream, wgt, part);
  hipLaunchKernelGGL(k_wquant,    dim3(64),       dim3(512), 0, stream, wgt, wq, part);
  hipLaunchKernelGGL(k_xquant,    dim3(Mdim/32),  dim3(512), 0, stream, x, xq, xs);
  hipLaunchKernelGGL(k_gemm,      dim3((Mdim/256)*(Ndim/128)), dim3(512), 0, stream,
                     xq, wq, xs, part, bias, out);
}

// Round 24
// 132.448 us; speedup vs baseline: 1.0121x; 1.0121x over previous
//
#include <hip/hip_runtime.h>
#include <stdint.h>

typedef int i32x4  __attribute__((ext_vector_type(4)));
typedef int i32x16 __attribute__((ext_vector_type(16)));

static constexpr int Mdim   = 16384;     // B*S = 8*2048
static constexpr int Kdim   = 2048;      // D_IN
static constexpr int Ndim   = 2048;      // D_OUT
static constexpr int WELEMS = Ndim * Kdim;   // 4194304

// Fragment-major pack layout (shared by packers and GEMM):
//   chunk(R, c) = 1024 B at base + (R*64 + c)*1024
//   byte l*16 + b of a chunk holds row R*32 + (l&31), k = c*32 + (l>>5)*16 + b

// ---------------- async global->LDS (16B per lane, lane-ordered dest) -------
__device__ __forceinline__ void gload_lds16(const void* g, void* l) {
  __builtin_amdgcn_global_load_lds(
      (const __attribute__((address_space(1))) void*)g,
      (__attribute__((address_space(3))) void*)l,
      16, 0, 0);
}

// ---------------- K1: partial sums of |w| (512 blocks) -----------------------
__global__ void k_abs_part(const float* __restrict__ w, float* __restrict__ part) {
  const float4* w4 = (const float4*)w;
  float s = 0.f;
  int idx = blockIdx.x * 256 + threadIdx.x;
  #pragma unroll 4
  for (int i = idx; i < WELEMS / 4; i += 512 * 256) {
    float4 v = w4[i];
    s += fabsf(v.x) + fabsf(v.y) + fabsf(v.z) + fabsf(v.w);
  }
  #pragma unroll
  for (int off = 32; off > 0; off >>= 1) s += __shfl_down(s, off);
  __shared__ float sm[4];
  if ((threadIdx.x & 63) == 0) sm[threadIdx.x >> 6] = s;
  __syncthreads();
  if (threadIdx.x == 0) part[blockIdx.x] = sm[0] + sm[1] + sm[2] + sm[3];
}

__device__ __forceinline__ int quant4(float4 v, float sc) {
  int a = (int)rintf(v.x / sc); a = a < -128 ? -128 : (a > 127 ? 127 : a);
  int b = (int)rintf(v.y / sc); b = b < -128 ? -128 : (b > 127 ? 127 : b);
  int c = (int)rintf(v.z / sc); c = c < -128 ? -128 : (c > 127 ? 127 : c);
  int d = (int)rintf(v.w / sc); d = d < -128 ? -128 : (d > 127 ? 127 : d);
  return (a & 255) | ((b & 255) << 8) | ((c & 255) << 16) | ((d & 255) << 24);
}

__device__ __forceinline__ int tern4(float4 v, float s) {
  int a = (int)rintf(v.x / s); a = a < -1 ? -1 : (a > 1 ? 1 : a);
  int b = (int)rintf(v.y / s); b = b < -1 ? -1 : (b > 1 ? 1 : b);
  int c = (int)rintf(v.z / s); c = c < -1 ? -1 : (c > 1 ? 1 : c);
  int d = (int)rintf(v.w / s); d = d < -1 ? -1 : (d > 1 ? 1 : d);
  return (a & 255) | ((b & 255) << 8) | ((c & 255) << 16) | ((d & 255) << 24);
}

// LDS row stride for the transpose buffers: 2052 B (513 dwords, odd ->
// bank = (l*513 + k)%32 spreads 32 rows over all 32 banks; <=2-way = free).
static constexpr int LSTR = 2052;

// ---------------- K3: ternary weight quantize + pack (inlines the scale) ----
__global__ __launch_bounds__(512) void k_wquant(const float* __restrict__ w,
                                                char* __restrict__ wq,
                                                const float* __restrict__ part) {
  __shared__ char sq[32 * LSTR];
  __shared__ float smr[8];
  const int wv = threadIdx.x >> 6;       // 0..7
  const int l  = threadIdx.x & 63;

  // ---- inline scale = mean(|w|): reduce part[0..511] ----
  float ps = part[threadIdx.x];          // 512 partials, block = 512
  #pragma unroll
  for (int off = 32; off > 0; off >>= 1) ps += __shfl_down(ps, off);
  if (l == 0) smr[wv] = ps;
  __syncthreads();
  const float s = (smr[0] + smr[1] + smr[2] + smr[3] +
                   smr[4] + smr[5] + smr[6] + smr[7]) / (float)WELEMS + 1e-8f;

  const int Rg = blockIdx.x;
  #pragma unroll
  for (int it = 0; it < 4; ++it) {
    const int rs = it * 8 + wv;          // row slot 0..31
    const float4* wr = (const float4*)(w + (size_t)(Rg * 32 + rs) * Kdim);
    #pragma unroll
    for (int c = 0; c < 8; ++c)
      *(int*)(&sq[rs * LSTR + (c * 64 + l) * 4]) = tern4(wr[c * 64 + l], s);
  }
  __syncthreads();
  char* dst = wq + (size_t)Rg * 65536;
  #pragma unroll
  for (int i = 0; i < 8; ++i) {
    const int c = i * 8 + wv;            // chunk 0..63
    int p[4];
    #pragma unroll
    for (int j = 0; j < 4; ++j)
      p[j] = *(const int*)(&sq[(l & 31) * LSTR + c * 32 + (l >> 5) * 16 + j * 4]);
    *(int4*)(dst + c * 1024 + l * 16) = make_int4(p[0], p[1], p[2], p[3]);
  }
}

// ---------------- K4: per-row absmax + int8 quantize + pack ------------------
// Rows processed in PAIRS per wave-iteration: both rows' loads (2 x 128 B/lane)
// are issued back-to-back so the second row's HBM latency hides under the
// first row's reduce/quant (more MLP at identical structure).
__global__ __launch_bounds__(512) void k_xquant(const float* __restrict__ x,
                                                char* __restrict__ xq,
                                                float* __restrict__ xs) {
  __shared__ char sq[32 * LSTR];
  const int Rg = blockIdx.x;
  const int wv = threadIdx.x >> 6;       // 0..7
  const int l  = threadIdx.x & 63;

  #pragma unroll
  for (int it = 0; it < 2; ++it) {
    const int rs0  = it * 16 + wv * 2;   // row slots rs0, rs0+1
    const int row0 = Rg * 32 + rs0;
    const float4* xr0 = (const float4*)(x + (size_t)row0 * Kdim);
    const float4* xr1 = (const float4*)(x + (size_t)(row0 + 1) * Kdim);
    float4 v0[8], v1[8];
    #pragma unroll
    for (int c = 0; c < 8; ++c) v0[c] = xr0[c * 64 + l];
    #pragma unroll
    for (int c = 0; c < 8; ++c) v1[c] = xr1[c * 64 + l];

    float m0 = 0.f, m1 = 0.f;
    #pragma unroll
    for (int c = 0; c < 8; ++c) {
      m0 = fmaxf(m0, fmaxf(fmaxf(fabsf(v0[c].x), fabsf(v0[c].y)),
                           fmaxf(fabsf(v0[c].z), fabsf(v0[c].w))));
      m1 = fmaxf(m1, fmaxf(fmaxf(fabsf(v1[c].x), fabsf(v1[c].y)),
                           fmaxf(fabsf(v1[c].z), fabsf(v1[c].w))));
    }
    #pragma unroll
    for (int off = 1; off < 64; off <<= 1) {
      m0 = fmaxf(m0, __shfl_xor(m0, off));
      m1 = fmaxf(m1, __shfl_xor(m1, off));
    }
    m0 = fmaxf(m0, 1e-8f);  m1 = fmaxf(m1, 1e-8f);
    const float sc0 = m0 / 127.0f, sc1 = m1 / 127.0f;
    if (l == 0) { xs[row0] = sc0; xs[row0 + 1] = sc1; }
    #pragma unroll
    for (int c = 0; c < 8; ++c) {
      *(int*)(&sq[rs0 * LSTR + (c * 64 + l) * 4])       = quant4(v0[c], sc0);
      *(int*)(&sq[(rs0 + 1) * LSTR + (c * 64 + l) * 4]) = quant4(v1[c], sc1);
    }
  }
  __syncthreads();
  char* dst = xq + (size_t)Rg * 65536;
  #pragma unroll
  for (int i = 0; i < 8; ++i) {
    const int c = i * 8 + wv;
    int p[4];
    #pragma unroll
    for (int j = 0; j < 4; ++j)
      p[j] = *(const int*)(&sq[(l & 31) * LSTR + c * 32 + (l >> 5) * 16 + j * 4]);
    *(int4*)(dst + c * 1024 + l * 16) = make_int4(p[0], p[1], p[2], p[3]);
  }
}

// ---------------- K5: int8 MFMA GEMM, 256x128, RING-3, reads-before-barrier -
// (R22 verbatim -- best measured: 81 us, MfmaUtil 36.9%)
// 512 thr = 8 waves (4M x 2N), wave tile 64x64 = acc[2][2], ring-3 x 24 KiB,
// vmcnt(3) counted, 2 blocks/CU = 16 waves.  TILE: {vmcnt(3); bar;
// ds_reads(t); STAGE(t+2); bar; setprio MFMA}.
__global__ __launch_bounds__(512, 4) void k_gemm(
    const char* __restrict__ xq, const char* __restrict__ wq,
    const float* __restrict__ xs, const float* __restrict__ scal_part,
    const float* __restrict__ bias, float* __restrict__ out) {
  __shared__ __attribute__((aligned(128))) char lds[3][24576];

  // XCD-aware bijective swizzle: 1024 blocks, 1024 % 8 == 0.
  const int hw  = blockIdx.x;
  const int lin = (hw & 7) * 128 + (hw >> 3);
  const int bm  = lin >> 4;               // 64 M-tiles (256 rows)
  const int bn  = lin & 15;               // 16 N-tiles (128 cols)

  const int tid = threadIdx.x;
  const int w   = tid >> 6;               // wave 0..7
  const int l   = tid & 63;
  const int wr  = w >> 1, wc = w & 1;     // 4 x 2 wave grid
  const int l16 = l * 16;

  // scale = mean(|w|): in-wave reduce of part[512] (8 vals/lane)
  float ps = scal_part[l]       + scal_part[l + 64]  + scal_part[l + 128] +
             scal_part[l + 192] + scal_part[l + 256] + scal_part[l + 320] +
             scal_part[l + 384] + scal_part[l + 448];
  #pragma unroll
  for (int off = 32; off > 0; off >>= 1) ps += __shfl_down(ps, off);
  const float wsc = __shfl(ps, 0) / (float)WELEMS;

  // staging map: q = w*3+j over 24 chunks = [A: rg 0..7 x ks 0,1][B: rg 0..3 x ks 0,1]
  const char* gsrc[3];
  int         loff[3];
  #pragma unroll
  for (int j = 0; j < 3; ++j) {
    const int q = w * 3 + j;             // wave-uniform
    if (q < 16) {
      const int rg = q >> 1, ks = q & 1;
      gsrc[j] = xq + (size_t)(bm * 8 + rg) * 65536 + ks * 1024 + l16;
      loff[j] = rg * 2048 + ks * 1024;
    } else {
      const int p = q - 16, rg = p >> 1, ks = p & 1;
      gsrc[j] = wq + (size_t)(bn * 4 + rg) * 65536 + ks * 1024 + l16;
      loff[j] = 16384 + rg * 2048 + ks * 1024;
    }
  }

#define STAGE(t_, buf_)                                                   \
  { const size_t kb_ = (size_t)(t_) * 2048;                               \
    gload_lds16(gsrc[0] + kb_, &lds[buf_][loff[0]]);                      \
    gload_lds16(gsrc[1] + kb_, &lds[buf_][loff[1]]);                      \
    gload_lds16(gsrc[2] + kb_, &lds[buf_][loff[2]]); }

  i32x16 acc[2][2] = {};

  STAGE(0, 0); STAGE(1, 1);               // 6 per-wave loads in flight

#define TILE(T_, RB_, SB_, VMTOK, DOSTG)                                    \
  {                                                                         \
    VMTOK                                                                   \
    __builtin_amdgcn_s_barrier();                                           \
    asm volatile("" ::: "memory");                                          \
    const char* base_ = &lds[RB_][0];                                       \
    i32x4 aF[2][2], bF[2][2];                                               \
    _Pragma("unroll") for (int mi = 0; mi < 2; ++mi)                        \
      _Pragma("unroll") for (int ks = 0; ks < 2; ++ks)                      \
        aF[mi][ks] = *(const i32x4*)(base_ + ((wr*2+mi)*2+ks)*1024 + l16);  \
    _Pragma("unroll") for (int ni = 0; ni < 2; ++ni)                        \
      _Pragma("unroll") for (int ks = 0; ks < 2; ++ks)                      \
        bF[ni][ks] = *(const i32x4*)(base_ + 16384 + ((wc*2+ni)*2+ks)*1024 + l16); \
    if (DOSTG) STAGE((T_) + 2, SB_)                                         \
    __builtin_amdgcn_s_barrier();                                           \
    asm volatile("" ::: "memory");                                          \
    __builtin_amdgcn_s_setprio(1);                                          \
    _Pragma("unroll") for (int ks = 0; ks < 2; ++ks)                        \
      _Pragma("unroll") for (int mi = 0; mi < 2; ++mi)                      \
        _Pragma("unroll") for (int ni = 0; ni < 2; ++ni)                    \
          acc[mi][ni] = __builtin_amdgcn_mfma_i32_32x32x32_i8(              \
              aF[mi][ks], bF[ni][ks], acc[mi][ni], 0, 0, 0);                \
    __builtin_amdgcn_s_setprio(0);                                          \
  }

#define VM3  asm volatile("s_waitcnt vmcnt(3)" ::: "memory");
#define VM0  asm volatile("s_waitcnt vmcnt(0)" ::: "memory");

  for (int t = 0; t < 30; t += 3) {       // tiles 0..29, static ring-3 idx
    TILE(t,     0, 2, VM3, 1);            // read buf0, stage t+2 -> buf2
    TILE(t + 1, 1, 0, VM3, 1);            // read buf1, stage t+3 -> buf0
    TILE(t + 2, 2, 1, VM3, 1);            // read buf2, stage t+4 -> buf1
  }
  TILE(30, 0, 0, VM3, 0);                 // tile 31's 3 loads stay in flight
  TILE(31, 1, 0, VM0, 0);                 // queue empties (last tile only)
#undef TILE
#undef STAGE
#undef VM3
#undef VM0

  // epilogue: C/D mapping col = lane&31, row = (r&3) + 8*(r>>2) + 4*(lane>>5)
  const int lhi = (l >> 5) * 4, lcol = l & 31;
  float bc[2];
  #pragma unroll
  for (int ni = 0; ni < 2; ++ni)
    bc[ni] = bias[bn * 128 + wc * 64 + ni * 32 + lcol];

  #pragma unroll
  for (int mi = 0; mi < 2; ++mi) {
    const int rb = bm * 256 + wr * 64 + mi * 32 + lhi;
    #pragma unroll
    for (int r = 0; r < 16; ++r) {
      const int   row = rb + (r & 3) + 8 * (r >> 2);
      const float sv  = wsc * xs[row];
      #pragma unroll
      for (int ni = 0; ni < 2; ++ni) {
        const int col = bn * 128 + wc * 64 + ni * 32 + lcol;
        out[(size_t)row * Ndim + col] = (float)acc[mi][ni][r] * sv + bc[ni];
      }
    }
  }
}

// ---------------- launch -----------------------------------------------------
extern "C" void kernel_launch(void* const* d_in, const int* in_sizes, int n_in,
                              void* d_out, int out_size, void* d_ws, size_t ws_size,
                              hipStream_t stream) {
  const float* x    = (const float*)d_in[0];
  const float* wgt  = (const float*)d_in[1];
  const float* bias = (const float*)d_in[2];
  float* out = (float*)d_out;

  float* ws_f = (float*)d_ws;
  float* part = ws_f + 64;          // 512 floats
  float* xs   = ws_f + 1024;        // 16384 floats
  char*  wq   = (char*)(ws_f + 20480);          // 4 MiB packed, 16B-aligned
  char*  xq   = wq + (size_t)WELEMS;            // 32 MiB packed, 16B-aligned

  hipLaunchKernelGGL(k_abs_part,  dim3(512),      dim3(256), 0, stream, wgt, part);
  hipLaunchKernelGGL(k_wquant,    dim3(64),       dim3(512), 0, stream, wgt, wq, part);
  hipLaunchKernelGGL(k_xquant,    dim3(Mdim/32),  dim3(512), 0, stream, x, xq, xs);
  hipLaunchKernelGGL(k_gemm,      dim3((Mdim/256)*(Ndim/128)), dim3(512), 0, stream,
                     xq, wq, xs, part, bias, out);
}

// Round 25
// 128.365 us; speedup vs baseline: 1.0443x; 1.0318x over previous
//
#include <hip/hip_runtime.h>
#include <stdint.h>

typedef int i32x4  __attribute__((ext_vector_type(4)));
typedef int i32x16 __attribute__((ext_vector_type(16)));

static constexpr int Mdim   = 16384;     // B*S = 8*2048
static constexpr int Kdim   = 2048;      // D_IN
static constexpr int Ndim   = 2048;      // D_OUT
static constexpr int WELEMS = Ndim * Kdim;   // 4194304

// Fragment-major pack layout (shared by packers and GEMM):
//   chunk(R, c) = 1024 B at base + (R*64 + c)*1024
//   byte l*16 + b of a chunk holds row R*32 + (l&31), k = c*32 + (l>>5)*16 + b

// ---------------- async global->LDS (16B per lane, lane-ordered dest) -------
__device__ __forceinline__ void gload_lds16(const void* g, void* l) {
  __builtin_amdgcn_global_load_lds(
      (const __attribute__((address_space(1))) void*)g,
      (__attribute__((address_space(3))) void*)l,
      16, 0, 0);
}

__device__ __forceinline__ int quant4(float4 v, float sc) {
  int a = (int)rintf(v.x / sc); a = a < -128 ? -128 : (a > 127 ? 127 : a);
  int b = (int)rintf(v.y / sc); b = b < -128 ? -128 : (b > 127 ? 127 : b);
  int c = (int)rintf(v.z / sc); c = c < -128 ? -128 : (c > 127 ? 127 : c);
  int d = (int)rintf(v.w / sc); d = d < -128 ? -128 : (d > 127 ? 127 : d);
  return (a & 255) | ((b & 255) << 8) | ((c & 255) << 16) | ((d & 255) << 24);
}

__device__ __forceinline__ int tern4(float4 v, float s) {
  int a = (int)rintf(v.x / s); a = a < -1 ? -1 : (a > 1 ? 1 : a);
  int b = (int)rintf(v.y / s); b = b < -1 ? -1 : (b > 1 ? 1 : b);
  int c = (int)rintf(v.z / s); c = c < -1 ? -1 : (c > 1 ? 1 : c);
  int d = (int)rintf(v.w / s); d = d < -1 ? -1 : (d > 1 ? 1 : d);
  return (a & 255) | ((b & 255) << 8) | ((c & 255) << 16) | ((d & 255) << 24);
}

// LDS row stride for the transpose buffers: 2052 B (513 dwords, odd ->
// bank = (l*513 + k)%32 spreads 32 rows over all 32 banks; <=2-way = free).
static constexpr int LSTR = 2052;

// ---------------- K2: per-row absmax + int8 quantize + pack, FUSED |w| sum --
// 512 blocks x 512 thr.  Each block additionally sums |w| over its 1/512
// slice (4 float4/thread, overlapped under the x stream) -> part[blockIdx].
__global__ __launch_bounds__(512) void k_xquant(const float* __restrict__ x,
                                                char* __restrict__ xq,
                                                float* __restrict__ xs,
                                                const float* __restrict__ w,
                                                float* __restrict__ part) {
  __shared__ char sq[32 * LSTR];
  __shared__ float smr[8];
  const int Rg = blockIdx.x;
  const int wv = threadIdx.x >> 6;       // 0..7
  const int l  = threadIdx.x & 63;

  // ---- fused |w| partial slice: issue loads first (overlap with x reads) --
  const float4* w4 = (const float4*)w;
  const int widx = Rg * 512 + threadIdx.x;
  float4 wv0 = w4[widx];
  float4 wv1 = w4[widx + 262144];
  float4 wv2 = w4[widx + 524288];
  float4 wv3 = w4[widx + 786432];

  #pragma unroll
  for (int it = 0; it < 4; ++it) {
    const int rs  = it * 8 + wv;
    const int row = Rg * 32 + rs;
    const float4* xr = (const float4*)(x + (size_t)row * Kdim);
    float4 v[8];
    float  m = 0.f;
    #pragma unroll
    for (int c = 0; c < 8; ++c) {
      v[c] = xr[c * 64 + l];
      m = fmaxf(m, fmaxf(fmaxf(fabsf(v[c].x), fabsf(v[c].y)),
                         fmaxf(fabsf(v[c].z), fabsf(v[c].w))));
    }
    #pragma unroll
    for (int off = 1; off < 64; off <<= 1) m = fmaxf(m, __shfl_xor(m, off));
    m = fmaxf(m, 1e-8f);
    const float sc = m / 127.0f;
    if (l == 0) xs[row] = sc;
    #pragma unroll
    for (int c = 0; c < 8; ++c)
      *(int*)(&sq[rs * LSTR + (c * 64 + l) * 4]) = quant4(v[c], sc);
  }

  // ---- reduce the |w| slice -> part[Rg] ----
  float swv = fabsf(wv0.x) + fabsf(wv0.y) + fabsf(wv0.z) + fabsf(wv0.w)
            + fabsf(wv1.x) + fabsf(wv1.y) + fabsf(wv1.z) + fabsf(wv1.w)
            + fabsf(wv2.x) + fabsf(wv2.y) + fabsf(wv2.z) + fabsf(wv2.w)
            + fabsf(wv3.x) + fabsf(wv3.y) + fabsf(wv3.z) + fabsf(wv3.w);
  #pragma unroll
  for (int off = 32; off > 0; off >>= 1) swv += __shfl_down(swv, off);
  if (l == 0) smr[wv] = swv;

  __syncthreads();
  if (threadIdx.x == 0)
    part[Rg] = smr[0] + smr[1] + smr[2] + smr[3] +
               smr[4] + smr[5] + smr[6] + smr[7];

  char* dst = xq + (size_t)Rg * 65536;
  #pragma unroll
  for (int i = 0; i < 8; ++i) {
    const int c = i * 8 + wv;
    int p[4];
    #pragma unroll
    for (int j = 0; j < 4; ++j)
      p[j] = *(const int*)(&sq[(l & 31) * LSTR + c * 32 + (l >> 5) * 16 + j * 4]);
    *(int4*)(dst + c * 1024 + l * 16) = make_int4(p[0], p[1], p[2], p[3]);
  }
}

// ---------------- K3: ternary weight quantize + pack (inlines the scale) ----
__global__ __launch_bounds__(512) void k_wquant(const float* __restrict__ w,
                                                char* __restrict__ wq,
                                                const float* __restrict__ part) {
  __shared__ char sq[32 * LSTR];
  __shared__ float smr[8];
  const int wv = threadIdx.x >> 6;       // 0..7
  const int l  = threadIdx.x & 63;

  // ---- inline scale = mean(|w|): reduce part[0..511] ----
  float ps = part[threadIdx.x];          // 512 partials, block = 512
  #pragma unroll
  for (int off = 32; off > 0; off >>= 1) ps += __shfl_down(ps, off);
  if (l == 0) smr[wv] = ps;
  __syncthreads();
  const float s = (smr[0] + smr[1] + smr[2] + smr[3] +
                   smr[4] + smr[5] + smr[6] + smr[7]) / (float)WELEMS + 1e-8f;

  const int Rg = blockIdx.x;
  #pragma unroll
  for (int it = 0; it < 4; ++it) {
    const int rs = it * 8 + wv;          // row slot 0..31
    const float4* wr = (const float4*)(w + (size_t)(Rg * 32 + rs) * Kdim);
    #pragma unroll
    for (int c = 0; c < 8; ++c)
      *(int*)(&sq[rs * LSTR + (c * 64 + l) * 4]) = tern4(wr[c * 64 + l], s);
  }
  __syncthreads();
  char* dst = wq + (size_t)Rg * 65536;
  #pragma unroll
  for (int i = 0; i < 8; ++i) {
    const int c = i * 8 + wv;            // chunk 0..63
    int p[4];
    #pragma unroll
    for (int j = 0; j < 4; ++j)
      p[j] = *(const int*)(&sq[(l & 31) * LSTR + c * 32 + (l >> 5) * 16 + j * 4]);
    *(int4*)(dst + c * 1024 + l * 16) = make_int4(p[0], p[1], p[2], p[3]);
  }
}

// ---------------- K5: int8 MFMA GEMM, 256x128, RING-3, reads-before-barrier -
// (R22 verbatim -- best measured: 81 us, MfmaUtil 36.9%)
// 512 thr = 8 waves (4M x 2N), wave tile 64x64 = acc[2][2], ring-3 x 24 KiB,
// vmcnt(3) counted, 2 blocks/CU = 16 waves.  TILE: {vmcnt(3); bar;
// ds_reads(t); STAGE(t+2); bar; setprio MFMA}.
__global__ __launch_bounds__(512, 4) void k_gemm(
    const char* __restrict__ xq, const char* __restrict__ wq,
    const float* __restrict__ xs, const float* __restrict__ scal_part,
    const float* __restrict__ bias, float* __restrict__ out) {
  __shared__ __attribute__((aligned(128))) char lds[3][24576];

  // XCD-aware bijective swizzle: 1024 blocks, 1024 % 8 == 0.
  const int hw  = blockIdx.x;
  const int lin = (hw & 7) * 128 + (hw >> 3);
  const int bm  = lin >> 4;               // 64 M-tiles (256 rows)
  const int bn  = lin & 15;               // 16 N-tiles (128 cols)

  const int tid = threadIdx.x;
  const int w   = tid >> 6;               // wave 0..7
  const int l   = tid & 63;
  const int wr  = w >> 1, wc = w & 1;     // 4 x 2 wave grid
  const int l16 = l * 16;

  // scale = mean(|w|): in-wave reduce of part[512] (8 vals/lane)
  float ps = scal_part[l]       + scal_part[l + 64]  + scal_part[l + 128] +
             scal_part[l + 192] + scal_part[l + 256] + scal_part[l + 320] +
             scal_part[l + 384] + scal_part[l + 448];
  #pragma unroll
  for (int off = 32; off > 0; off >>= 1) ps += __shfl_down(ps, off);
  const float wsc = __shfl(ps, 0) / (float)WELEMS;

  // staging map: q = w*3+j over 24 chunks = [A: rg 0..7 x ks 0,1][B: rg 0..3 x ks 0,1]
  const char* gsrc[3];
  int         loff[3];
  #pragma unroll
  for (int j = 0; j < 3; ++j) {
    const int q = w * 3 + j;             // wave-uniform
    if (q < 16) {
      const int rg = q >> 1, ks = q & 1;
      gsrc[j] = xq + (size_t)(bm * 8 + rg) * 65536 + ks * 1024 + l16;
      loff[j] = rg * 2048 + ks * 1024;
    } else {
      const int p = q - 16, rg = p >> 1, ks = p & 1;
      gsrc[j] = wq + (size_t)(bn * 4 + rg) * 65536 + ks * 1024 + l16;
      loff[j] = 16384 + rg * 2048 + ks * 1024;
    }
  }

#define STAGE(t_, buf_)                                                   \
  { const size_t kb_ = (size_t)(t_) * 2048;                               \
    gload_lds16(gsrc[0] + kb_, &lds[buf_][loff[0]]);                      \
    gload_lds16(gsrc[1] + kb_, &lds[buf_][loff[1]]);                      \
    gload_lds16(gsrc[2] + kb_, &lds[buf_][loff[2]]); }

  i32x16 acc[2][2] = {};

  STAGE(0, 0); STAGE(1, 1);               // 6 per-wave loads in flight

#define TILE(T_, RB_, SB_, VMTOK, DOSTG)                                    \
  {                                                                         \
    VMTOK                                                                   \
    __builtin_amdgcn_s_barrier();                                           \
    asm volatile("" ::: "memory");                                          \
    const char* base_ = &lds[RB_][0];                                       \
    i32x4 aF[2][2], bF[2][2];                                               \
    _Pragma("unroll") for (int mi = 0; mi < 2; ++mi)                        \
      _Pragma("unroll") for (int ks = 0; ks < 2; ++ks)                      \
        aF[mi][ks] = *(const i32x4*)(base_ + ((wr*2+mi)*2+ks)*1024 + l16);  \
    _Pragma("unroll") for (int ni = 0; ni < 2; ++ni)                        \
      _Pragma("unroll") for (int ks = 0; ks < 2; ++ks)                      \
        bF[ni][ks] = *(const i32x4*)(base_ + 16384 + ((wc*2+ni)*2+ks)*1024 + l16); \
    if (DOSTG) STAGE((T_) + 2, SB_)                                         \
    __builtin_amdgcn_s_barrier();                                           \
    asm volatile("" ::: "memory");                                          \
    __builtin_amdgcn_s_setprio(1);                                          \
    _Pragma("unroll") for (int ks = 0; ks < 2; ++ks)                        \
      _Pragma("unroll") for (int mi = 0; mi < 2; ++mi)                      \
        _Pragma("unroll") for (int ni = 0; ni < 2; ++ni)                    \
          acc[mi][ni] = __builtin_amdgcn_mfma_i32_32x32x32_i8(              \
              aF[mi][ks], bF[ni][ks], acc[mi][ni], 0, 0, 0);                \
    __builtin_amdgcn_s_setprio(0);                                          \
  }

#define VM3  asm volatile("s_waitcnt vmcnt(3)" ::: "memory");
#define VM0  asm volatile("s_waitcnt vmcnt(0)" ::: "memory");

  for (int t = 0; t < 30; t += 3) {       // tiles 0..29, static ring-3 idx
    TILE(t,     0, 2, VM3, 1);            // read buf0, stage t+2 -> buf2
    TILE(t + 1, 1, 0, VM3, 1);            // read buf1, stage t+3 -> buf0
    TILE(t + 2, 2, 1, VM3, 1);            // read buf2, stage t+4 -> buf1
  }
  TILE(30, 0, 0, VM3, 0);                 // tile 31's 3 loads stay in flight
  TILE(31, 1, 0, VM0, 0);                 // queue empties (last tile only)
#undef TILE
#undef STAGE
#undef VM3
#undef VM0

  // epilogue: C/D mapping col = lane&31, row = (r&3) + 8*(r>>2) + 4*(lane>>5)
  const int lhi = (l >> 5) * 4, lcol = l & 31;
  float bc[2];
  #pragma unroll
  for (int ni = 0; ni < 2; ++ni)
    bc[ni] = bias[bn * 128 + wc * 64 + ni * 32 + lcol];

  #pragma unroll
  for (int mi = 0; mi < 2; ++mi) {
    const int rb = bm * 256 + wr * 64 + mi * 32 + lhi;
    #pragma unroll
    for (int r = 0; r < 16; ++r) {
      const int   row = rb + (r & 3) + 8 * (r >> 2);
      const float sv  = wsc * xs[row];
      #pragma unroll
      for (int ni = 0; ni < 2; ++ni) {
        const int col = bn * 128 + wc * 64 + ni * 32 + lcol;
        out[(size_t)row * Ndim + col] = (float)acc[mi][ni][r] * sv + bc[ni];
      }
    }
  }
}

// ---------------- launch -----------------------------------------------------
extern "C" void kernel_launch(void* const* d_in, const int* in_sizes, int n_in,
                              void* d_out, int out_size, void* d_ws, size_t ws_size,
                              hipStream_t stream) {
  const float* x    = (const float*)d_in[0];
  const float* wgt  = (const float*)d_in[1];
  const float* bias = (const float*)d_in[2];
  float* out = (float*)d_out;

  float* ws_f = (float*)d_ws;
  float* part = ws_f + 64;          // 512 floats
  float* xs   = ws_f + 1024;        // 16384 floats
  char*  wq   = (char*)(ws_f + 20480);          // 4 MiB packed, 16B-aligned
  char*  xq   = wq + (size_t)WELEMS;            // 32 MiB packed, 16B-aligned

  hipLaunchKernelGGL(k_xquant, dim3(Mdim/32), dim3(512), 0, stream, x, xq, xs, wgt, part);
  hipLaunchKernelGGL(k_wquant, dim3(64),      dim3(512), 0, stream, wgt, wq, part);
  hipLaunchKernelGGL(k_gemm,   dim3((Mdim/256)*(Ndim/128)), dim3(512), 0, stream,
                     xq, wq, xs, part, bias, out);
}